// Round 10
// baseline (162.415 us; speedup 1.0000x reference)
//
#include <hip/hip_runtime.h>

#define N_NODES 50000
#define N_EDGES 1600000
#define D_IN    256
#define HS      32

#define NB      400    // row buckets
#define ROWS_PB 125    // rows per bucket (400*125 = 50000 exactly)
#define CAP     5120   // slots per bucket (mean 4000, std ~63)
#define EPB     4096   // edges per bin block (16 per thread)

#define MTILE   64     // proj rows per tile (4 waves x 16 rows)
#define PROJ_B  ((N_NODES + MTILE - 1) / MTILE)   // 782
#define BIN_B   ((N_EDGES + EPB - 1) / EPB)       // 391
#define WFRAG_B 6      // 6 blocks x 256 x 16 = 24576 wfrag elements

typedef __bf16 bf16x8 __attribute__((ext_vector_type(8)));
typedef float  floatx4 __attribute__((ext_vector_type(4)));

static __device__ __forceinline__ unsigned short f2bf(float f) {
    unsigned u = __float_as_uint(f);
    return (unsigned short)((u + 0x7FFFu + ((u >> 16) & 1u)) >> 16);  // RNE
}

// ---------------------------------------------------------------------------
// K1: bin (blocks 0..390) ∥ wfrag (blocks 391..396). Independent work — the
// 6 wfrag blocks hide entirely under bin's tail.
//   bin: LDS histogram -> one global claim per (block,bucket) -> packed
//        (local_row<<16 | col) writes from a 16-edge register cache.
//   wfrag: W -> bf16 B-fragments for mfma_f32_16x16x32_bf16:
//        wfrag[(((s*6+t)*64+lane)*8)+j] = W[k=s*32+(lane>>4)*8+j][n=t*16+(lane&15)]
// ---------------------------------------------------------------------------
__global__ __launch_bounds__(256) void bin_wfrag_kernel(
    const int* __restrict__ er, const int* __restrict__ ec,
    int* __restrict__ fill, unsigned int* __restrict__ pairs,
    const float* __restrict__ Wq, const float* __restrict__ Wk,
    const float* __restrict__ Wv, unsigned short* __restrict__ wfrag)
{
    __shared__ int lcnt[NB];   // 1.6 KB
    const int t = threadIdx.x;

    if (blockIdx.x < BIN_B) {
        // ---------------- edge binning ----------------
        const int e0 = blockIdx.x * EPB;
        const int e1 = min(e0 + EPB, N_EDGES);

        for (int b = t; b < NB; b += 256) lcnt[b] = 0;
        __syncthreads();

        int rl[16], cl[16];
#pragma unroll
        for (int i = 0; i < 16; i++) {
            const int e = e0 + t + i * 256;
            if (e < e1) {
                rl[i] = er[e];
                cl[i] = ec[e];
                atomicAdd(&lcnt[rl[i] / ROWS_PB], 1);
            }
        }
        __syncthreads();

        for (int b = t; b < NB; b += 256) {
            const int c = lcnt[b];
            lcnt[b] = (c > 0) ? atomicAdd(&fill[b], c) : 0;  // base slot
        }
        __syncthreads();

#pragma unroll
        for (int i = 0; i < 16; i++) {
            const int e = e0 + t + i * 256;
            if (e < e1) {
                const int r = rl[i];
                const int b = r / ROWS_PB;
                const int slot = atomicAdd(&lcnt[b], 1);
                pairs[(size_t)b * CAP + slot] =
                    ((unsigned)(r - b * ROWS_PB) << 16) | (unsigned)cl[i];
            }
        }
    } else {
        // ---------------- W fragment generation ----------------
        const int wb = blockIdx.x - BIN_B;   // 0..5
#pragma unroll
        for (int ii = 0; ii < 16; ii++) {
            const int i = wb * 4096 + ii * 256 + t;   // 0..24575
            const int j    = i & 7;
            const int lane = (i >> 3) & 63;
            const int st   = i >> 9;
            const int tt   = st % 6;
            const int s    = st / 6;
            const int k    = s * 32 + (lane >> 4) * 8 + j;
            const int col  = tt * 16 + (lane & 15);
            float v;
            if      (col < 32) v = Wq[k * HS + col];
            else if (col < 64) v = Wk[k * HS + (col - 32)];
            else               v = Wv[k * HS + (col - 64)];
            wfrag[i] = f2bf(v);
        }
    }
}

// ---------------------------------------------------------------------------
// K2: place (blocks 0..399, dispatched first — long per-block latency chains)
// ∥ proj (blocks 400..1181, throughput MFMA). place depends on bin (K1),
// proj depends on wfrag (K1); mutually independent.
//   place: self-computed base (reduction of fill[0..b-1]); LDS row-histogram
//     + scan from a 20-entry register cache; DIRECT scattered stores to
//     col_sorted — each bucket's 16 KB window is written wholly by this
//     block so lines fill without an LDS staging pass (LDS now ~2 KB).
//   proj: LDS-free MFMA; lane's A-fragment = 8 contiguous fp32 of one X row,
//     converted to bf16 in registers. C layout col=lane&15, row=quad*4+i.
// ---------------------------------------------------------------------------
__global__ __launch_bounds__(256) void place_proj_kernel(
    const unsigned int* __restrict__ pairs, const int* __restrict__ fill,
    int* __restrict__ rowptr, int* __restrict__ col_sorted,
    const float* __restrict__ X, const unsigned short* __restrict__ wfrag,
    float* __restrict__ Q, unsigned int* __restrict__ KVp)
{
    __shared__ int cnt_l[ROWS_PB];
    __shared__ int s[128];
    __shared__ int red[256];

    const int t = threadIdx.x;

    if (blockIdx.x < NB) {
        // ---------------- placement ----------------
        const int b = blockIdx.x;
        const int n = fill[b];
        const unsigned int* pb = pairs + (size_t)b * CAP;

        int partial = 0;
        for (int i = t; i < b; i += 256) partial += fill[i];
        red[t] = partial;
        for (int i = t; i < ROWS_PB; i += 256) cnt_l[i] = 0;
        __syncthreads();
#pragma unroll
        for (int ofs = 128; ofs > 0; ofs >>= 1) {
            if (t < ofs) red[t] += red[t + ofs];
            __syncthreads();
        }
        const int base = red[0];

        unsigned pl[20];
#pragma unroll
        for (int k = 0; k < 20; k++) {
            const int i = t + k * 256;
            if (i < n) {
                pl[k] = pb[i];
                atomicAdd(&cnt_l[pl[k] >> 16], 1);
            }
        }
        __syncthreads();

        if (t < 128) s[t] = (t < ROWS_PB) ? cnt_l[t] : 0;
        __syncthreads();
#pragma unroll
        for (int ofs = 1; ofs < 128; ofs <<= 1) {
            const int u = (t < 128 && t >= ofs) ? s[t - ofs] : 0;
            __syncthreads();
            if (t < 128) s[t] += u;
            __syncthreads();
        }
        int gcur = 0;
        if (t < ROWS_PB) {
            gcur = base + s[t] - cnt_l[t];     // global start of this row
            rowptr[b * ROWS_PB + t] = gcur;
        }
        __syncthreads();
        if (t < ROWS_PB) cnt_l[t] = gcur;      // global placement cursor
        if (b == NB - 1 && t == 0) rowptr[N_NODES] = N_EDGES;
        __syncthreads();

#pragma unroll
        for (int k = 0; k < 20; k++) {
            const int i = t + k * 256;
            if (i < n) {
                const unsigned p = pl[k];
                const int pos = atomicAdd(&cnt_l[p >> 16], 1);
                col_sorted[pos] = (int)(p & 0xFFFFu);
            }
        }
    } else {
        // ---------------- projection (per-wave independent) ----------------
        const int pb   = blockIdx.x - NB;
        const int lane = t & 63;
        const int w    = t >> 6;
        const int quad = lane >> 4;
        const int m16  = lane & 15;
        const int row0 = pb * MTILE;

        int ar = row0 + w * 16 + m16;
        if (ar >= N_NODES) ar = N_NODES - 1;    // clamp; C rows are guarded
        const float* xrow = X + (size_t)ar * D_IN;

        floatx4 acc[6];
#pragma unroll
        for (int nt = 0; nt < 6; nt++) acc[nt] = (floatx4)0.f;

#pragma unroll
        for (int ss = 0; ss < 8; ss++) {
            const float4 xa = *(const float4*)(xrow + ss * 32 + quad * 8);
            const float4 xb = *(const float4*)(xrow + ss * 32 + quad * 8 + 4);
            bf16x8 bfr[6];
#pragma unroll
            for (int nt = 0; nt < 6; nt++)
                bfr[nt] = *(const bf16x8*)(wfrag + (((ss * 6 + nt) * 64 + lane) * 8));
            union { bf16x8 v; unsigned short u[8]; } afr;
            afr.u[0] = f2bf(xa.x); afr.u[1] = f2bf(xa.y);
            afr.u[2] = f2bf(xa.z); afr.u[3] = f2bf(xa.w);
            afr.u[4] = f2bf(xb.x); afr.u[5] = f2bf(xb.y);
            afr.u[6] = f2bf(xb.z); afr.u[7] = f2bf(xb.w);
#pragma unroll
            for (int nt = 0; nt < 6; nt++)
                acc[nt] = __builtin_amdgcn_mfma_f32_16x16x32_bf16(afr.v, bfr[nt], acc[nt], 0, 0, 0);
        }

#pragma unroll
        for (int i = 0; i < 4; i++) {
            const int gr = row0 + w * 16 + quad * 4 + i;
            if (gr < N_NODES) {
#pragma unroll
                for (int nt = 0; nt < 2; nt++)
                    Q[gr * HS + nt * 16 + m16] = acc[nt][i];
#pragma unroll
                for (int p = 0; p < 2; p++) {
                    const int j = p * 16 + m16;
                    const unsigned kb = f2bf(acc[2 + p][i]);
                    const unsigned vb = f2bf(acc[4 + p][i]);
                    KVp[gr * HS + j] = (kb << 16) | vb;
                }
            }
        }
    }
}

// ---------------------------------------------------------------------------
// K3: aggregation. One wave per row; lane = slot*8+comp. 32 edges/iter as 4
// wave-uniform-guarded batches of 8: col loads, then KV gathers, then
// compute. K = hi16, V = lo16. No atomics.
// ---------------------------------------------------------------------------
__global__ __launch_bounds__(256) void aggregate_kernel(
    const int* __restrict__ rowptr, const int* __restrict__ col,
    const float* __restrict__ Q, const unsigned int* __restrict__ KVp,
    float* __restrict__ out)
{
    const int lane = threadIdx.x & 63;
    const int r    = (blockIdx.x * blockDim.x + threadIdx.x) >> 6;
    if (r >= N_NODES) return;
    const int comp = lane & 7;
    const int slot = lane >> 3;

    const float4 q4 = *(const float4*)(Q + r * HS + comp * 4);
    const int start = rowptr[r];
    const int end   = rowptr[r + 1];
    const int last  = end - 1;
    const float scale = 0.17677669529663687f;  // 1/sqrt(32)

    float accD = 0.f;
    float n0 = 0.f, n1 = 0.f, n2 = 0.f, n3 = 0.f;

    for (int e0 = start; e0 < end; e0 += 32) {
        int   cc[4];
        uint4 kv[4];
#pragma unroll
        for (int b = 0; b < 4; b++)
            if (e0 + 8 * b < end)
                cc[b] = col[min(e0 + 8 * b + slot, last)];
#pragma unroll
        for (int b = 0; b < 4; b++)
            if (e0 + 8 * b < end)
                kv[b] = *(const uint4*)(KVp + (size_t)cc[b] * HS + comp * 4);
#pragma unroll
        for (int b = 0; b < 4; b++) {
            if (e0 + 8 * b < end) {
                float p = q4.x * __uint_as_float(kv[b].x & 0xFFFF0000u)
                        + q4.y * __uint_as_float(kv[b].y & 0xFFFF0000u)
                        + q4.z * __uint_as_float(kv[b].z & 0xFFFF0000u)
                        + q4.w * __uint_as_float(kv[b].w & 0xFFFF0000u);
#pragma unroll
                for (int ofs = 1; ofs < 8; ofs <<= 1)
                    p += __shfl_xor(p, ofs, 64);
                const float ex = (e0 + 8 * b + slot < end) ? __expf(p * scale) : 0.f;
                accD += ex;
                n0 += ex * __uint_as_float(kv[b].x << 16);
                n1 += ex * __uint_as_float(kv[b].y << 16);
                n2 += ex * __uint_as_float(kv[b].z << 16);
                n3 += ex * __uint_as_float(kv[b].w << 16);
            }
        }
    }

#pragma unroll
    for (int ofs = 8; ofs < 64; ofs <<= 1) {
        accD += __shfl_xor(accD, ofs, 64);
        n0 += __shfl_xor(n0, ofs, 64);
        n1 += __shfl_xor(n1, ofs, 64);
        n2 += __shfl_xor(n2, ofs, 64);
        n3 += __shfl_xor(n3, ofs, 64);
    }

    if (slot == 0) {
        const float inv = (accD > 0.f) ? 1.f / accD : 0.f;
        float4 o;
        o.x = n0 * inv; o.y = n1 * inv; o.z = n2 * inv; o.w = n3 * inv;
        *(float4*)(out + r * HS + comp * 4) = o;
    }
}

extern "C" void kernel_launch(void* const* d_in, const int* in_sizes, int n_in,
                              void* d_out, int out_size, void* d_ws, size_t ws_size,
                              hipStream_t stream)
{
    const float* X  = (const float*)d_in[0];
    const float* Wq = (const float*)d_in[1];
    const float* Wk = (const float*)d_in[2];
    const float* Wv = (const float*)d_in[3];
    const int*   ei = (const int*)d_in[4];
    const int* er = ei;
    const int* ec = ei + N_EDGES;

    float* out = (float*)d_out;

    // workspace: Q | KVp | fill | rowptr | wfrag | pairs | col_sorted
    float* Q          = (float*)d_ws;
    unsigned int* KVp = (unsigned int*)(Q + (size_t)N_NODES * HS);
    int* fill         = (int*)(KVp + (size_t)N_NODES * HS);
    int* rowptr       = fill + NB;
    unsigned short* wfrag = (unsigned short*)(rowptr + (N_NODES + 1));
    unsigned int* pairs   = (unsigned int*)(wfrag + 8 * 6 * 64 * 8);
    int* col_sorted   = (int*)(pairs + (size_t)NB * CAP);

    hipMemsetAsync(fill, 0, NB * sizeof(int), stream);

    bin_wfrag_kernel<<<BIN_B + WFRAG_B, 256, 0, stream>>>(
        er, ec, fill, pairs, Wq, Wk, Wv, wfrag);

    place_proj_kernel<<<NB + PROJ_B, 256, 0, stream>>>(
        pairs, fill, rowptr, col_sorted, X, wfrag, Q, KVp);

    aggregate_kernel<<<(N_NODES * 64 + 255) / 256, 256, 0, stream>>>(
        rowptr, col_sorted, Q, KVp, out);
}

// Round 12
// 159.144 us; speedup vs baseline: 1.0205x; 1.0205x over previous
//
#include <hip/hip_runtime.h>

#define N_NODES 50000
#define N_EDGES 1600000
#define D_IN    256
#define HS      32

#define NB      400    // row buckets
#define ROWS_PB 125    // rows per bucket (400*125 = 50000 exactly)
#define CAP     5120   // slots per bucket (mean 4000, std ~63)
#define EPB     4096   // edges per bin-phase block (16 per thread)

#define MTILE   64     // proj rows per block
#define XPITCH  264    // LDS row pitch in bf16 (256 + 8 pad)
#define PROJ_B  ((N_NODES + MTILE - 1) / MTILE)   // 782
#define BIN_B   ((N_EDGES + EPB - 1) / EPB)       // 391  (= PROJ_B/2 exactly)

typedef __bf16 bf16x8 __attribute__((ext_vector_type(8)));
typedef float  floatx4 __attribute__((ext_vector_type(4)));

static __device__ __forceinline__ unsigned short f2bf(float f) {
    unsigned u = __float_as_uint(f);
    return (unsigned short)((u + 0x7FFFu + ((u >> 16) & 1u)) >> 16);  // RNE
}

// ---------------------------------------------------------------------------
// Pre-kernel: W -> bf16 B-fragments for mfma_f32_16x16x32_bf16.
// wfrag[(((s*6+t)*64+lane)*8)+j] = W[k=s*32+(lane>>4)*8+j][n=t*16+(lane&15)]
// of combined [256,96]. Block 0 also zeroes `fill` and sets rowptr[N].
// ---------------------------------------------------------------------------
__global__ __launch_bounds__(256) void wfrag_kernel(
    const float* __restrict__ Wq, const float* __restrict__ Wk,
    const float* __restrict__ Wv, unsigned short* __restrict__ wfrag,
    int* __restrict__ fill, int* __restrict__ rowptr)
{
    if (blockIdx.x == 0) {
        for (int b = threadIdx.x; b < NB; b += 256) fill[b] = 0;
        if (threadIdx.x == 0) rowptr[N_NODES] = N_EDGES;
    }
    const int i = blockIdx.x * blockDim.x + threadIdx.x;
    if (i >= 8 * 6 * 64 * 8) return;
    const int j    = i & 7;
    const int lane = (i >> 3) & 63;
    const int st   = i >> 9;
    const int t    = st % 6;
    const int s    = st / 6;
    const int k    = s * 32 + (lane >> 4) * 8 + j;
    const int col  = t * 16 + (lane & 15);
    float v;
    if      (col < 32) v = Wq[k * HS + col];
    else if (col < 64) v = Wk[k * HS + (col - 32)];
    else               v = Wv[k * HS + (col - 64)];
    wfrag[i] = f2bf(v);
}

// ---------------------------------------------------------------------------
// Fused kernel: blocks with blockIdx%3 != 2 do the MFMA projection (782
// blocks); blocks with blockIdx%3 == 2 do edge binning (391 blocks). The two
// phases touch disjoint data (X/wfrag vs edge_index) so they overlap on the
// machine instead of serializing. (R11 note: cooperative-launch variant of
// this pipeline fails graph capture — plain launches only.)
// ---------------------------------------------------------------------------
__global__ __launch_bounds__(256) void proj_bin_kernel(
    const float* __restrict__ X, const unsigned short* __restrict__ wfrag,
    float* __restrict__ Q, unsigned int* __restrict__ KVp,
    const int* __restrict__ er, const int* __restrict__ ec,
    int* __restrict__ fill, unsigned int* __restrict__ pairs)
{
    __shared__ __align__(16) unsigned short xs[MTILE * XPITCH];   // 33 KB

    const int t = threadIdx.x;
    const int mod = blockIdx.x % 3;

    if (mod != 2) {
        // ---------------- projection ----------------
        const int pb   = (blockIdx.x / 3) * 2 + mod;
        const int lane = t & 63;
        const int w    = t >> 6;
        const int quad = lane >> 4;
        const int m16  = lane & 15;
        const int row0 = pb * MTILE;

#pragma unroll
        for (int it = 0; it < (MTILE * 64) / 256; it++) {
            const int idx = it * 256 + t;
            const int r   = idx >> 6;
            const int c4  = idx & 63;
            int gr = row0 + r;
            if (gr >= N_NODES) gr = N_NODES - 1;   // clamp; never stored
            const float4 xv = *(const float4*)(X + (size_t)gr * D_IN + c4 * 4);
            ushort4 b;
            b.x = f2bf(xv.x); b.y = f2bf(xv.y); b.z = f2bf(xv.z); b.w = f2bf(xv.w);
            *(ushort4*)(&xs[r * XPITCH + c4 * 4]) = b;
        }
        __syncthreads();

        floatx4 acc[6];
#pragma unroll
        for (int nt = 0; nt < 6; nt++) acc[nt] = (floatx4)0.f;

        const int arow = w * 16 + m16;

#pragma unroll
        for (int s = 0; s < 8; s++) {
            bf16x8 bfr[6];
#pragma unroll
            for (int nt = 0; nt < 6; nt++)
                bfr[nt] = *(const bf16x8*)(wfrag + (((s * 6 + nt) * 64 + lane) * 8));
            const bf16x8 afr = *(const bf16x8*)(&xs[arow * XPITCH + s * 32 + quad * 8]);
#pragma unroll
            for (int nt = 0; nt < 6; nt++)
                acc[nt] = __builtin_amdgcn_mfma_f32_16x16x32_bf16(afr, bfr[nt], acc[nt], 0, 0, 0);
        }

        // epilogue: C layout col=lane&15, row=(lane>>4)*4+i  [m89]
#pragma unroll
        for (int i = 0; i < 4; i++) {
            const int gr = row0 + w * 16 + quad * 4 + i;
            if (gr < N_NODES) {
#pragma unroll
                for (int nt = 0; nt < 2; nt++)
                    Q[gr * HS + nt * 16 + m16] = acc[nt][i];
#pragma unroll
                for (int p = 0; p < 2; p++) {
                    const int j = p * 16 + m16;
                    const unsigned kb = f2bf(acc[2 + p][i]);
                    const unsigned vb = f2bf(acc[4 + p][i]);
                    KVp[gr * HS + j] = (kb << 16) | vb;
                }
            }
        }
    } else {
        // ---------------- edge binning ----------------
        int* lcnt = (int*)xs;   // reuse LDS (block-uniform branch)
        const int bb = blockIdx.x / 3;
        const int e0 = bb * EPB;
        const int e1 = min(e0 + EPB, N_EDGES);

        for (int b = t; b < NB; b += 256) lcnt[b] = 0;
        __syncthreads();

        int rl[16], cl[16];
#pragma unroll
        for (int i = 0; i < 16; i++) {
            const int e = e0 + t + i * 256;
            if (e < e1) {
                rl[i] = er[e];
                cl[i] = ec[e];
                atomicAdd(&lcnt[rl[i] / ROWS_PB], 1);
            }
        }
        __syncthreads();

        for (int b = t; b < NB; b += 256) {
            const int c = lcnt[b];
            lcnt[b] = (c > 0) ? atomicAdd(&fill[b], c) : 0;  // base slot
        }
        __syncthreads();

#pragma unroll
        for (int i = 0; i < 16; i++) {
            const int e = e0 + t + i * 256;
            if (e < e1) {
                const int r = rl[i];
                const int b = r / ROWS_PB;
                const int slot = atomicAdd(&lcnt[b], 1);
                pairs[(size_t)b * CAP + slot] =
                    ((unsigned)(r - b * ROWS_PB) << 16) | (unsigned)cl[i];
            }
        }
    }
}

// ---------------------------------------------------------------------------
// Phase B: one block per bucket. Computes its own base offset (reduction of
// fill[0..b-1], L2-broadcast), then LDS row-histogram + scan + staging;
// emits rowptr; coalesced copy-out.
// ---------------------------------------------------------------------------
__global__ __launch_bounds__(256) void place_kernel(
    const unsigned int* __restrict__ pairs, const int* __restrict__ fill,
    int* __restrict__ rowptr, int* __restrict__ col_sorted)
{
    __shared__ int cnt_l[ROWS_PB];
    __shared__ int s[128];
    __shared__ int red[256];
    __shared__ int stage[CAP];

    const int b = blockIdx.x;
    const int t = threadIdx.x;
    const int n = fill[b];
    const unsigned int* pb = pairs + (size_t)b * CAP;

    // base = sum of fill[0..b-1]
    int partial = 0;
    for (int i = t; i < b; i += 256) partial += fill[i];
    red[t] = partial;
    for (int i = t; i < ROWS_PB; i += 256) cnt_l[i] = 0;
    __syncthreads();
#pragma unroll
    for (int ofs = 128; ofs > 0; ofs >>= 1) {
        if (t < ofs) red[t] += red[t + ofs];
        __syncthreads();
    }
    const int base = red[0];

    unsigned pl[20];
#pragma unroll
    for (int k = 0; k < 20; k++) {
        const int i = t + k * 256;
        if (i < n) {
            pl[k] = pb[i];
            atomicAdd(&cnt_l[pl[k] >> 16], 1);
        }
    }
    __syncthreads();

    if (t < 128) s[t] = (t < ROWS_PB) ? cnt_l[t] : 0;
    __syncthreads();
#pragma unroll
    for (int ofs = 1; ofs < 128; ofs <<= 1) {
        const int u = (t < 128 && t >= ofs) ? s[t - ofs] : 0;
        __syncthreads();
        if (t < 128) s[t] += u;
        __syncthreads();
    }
    int excl = 0;
    if (t < ROWS_PB) {
        excl = s[t] - cnt_l[t];
        rowptr[b * ROWS_PB + t] = base + excl;
    }
    __syncthreads();
    if (t < ROWS_PB) cnt_l[t] = excl;
    __syncthreads();

#pragma unroll
    for (int k = 0; k < 20; k++) {
        const int i = t + k * 256;
        if (i < n) {
            const unsigned p = pl[k];
            const int pos = atomicAdd(&cnt_l[p >> 16], 1);
            stage[pos] = (int)(p & 0xFFFFu);
        }
    }
    __syncthreads();

    for (int i = t; i < n; i += 256)
        col_sorted[base + i] = stage[i];
}

// ---------------------------------------------------------------------------
// Aggregation: one wave per row; lane = slot*8+comp. 32 edges per iteration
// as 4 guarded batches of 8 (wave-uniform guards): col loads, then KV
// gathers, then compute. K = hi16, V = lo16. No atomics.
// ---------------------------------------------------------------------------
__global__ __launch_bounds__(256) void aggregate_kernel(
    const int* __restrict__ rowptr, const int* __restrict__ col,
    const float* __restrict__ Q, const unsigned int* __restrict__ KVp,
    float* __restrict__ out)
{
    const int lane = threadIdx.x & 63;
    const int r    = (blockIdx.x * blockDim.x + threadIdx.x) >> 6;
    if (r >= N_NODES) return;
    const int comp = lane & 7;
    const int slot = lane >> 3;

    const float4 q4 = *(const float4*)(Q + r * HS + comp * 4);
    const int start = rowptr[r];
    const int end   = rowptr[r + 1];
    const int last  = end - 1;
    const float scale = 0.17677669529663687f;  // 1/sqrt(32)

    float accD = 0.f;
    float n0 = 0.f, n1 = 0.f, n2 = 0.f, n3 = 0.f;

    for (int e0 = start; e0 < end; e0 += 32) {
        int   cc[4];
        uint4 kv[4];
#pragma unroll
        for (int b = 0; b < 4; b++)
            if (e0 + 8 * b < end)
                cc[b] = col[min(e0 + 8 * b + slot, last)];
#pragma unroll
        for (int b = 0; b < 4; b++)
            if (e0 + 8 * b < end)
                kv[b] = *(const uint4*)(KVp + (size_t)cc[b] * HS + comp * 4);
#pragma unroll
        for (int b = 0; b < 4; b++) {
            if (e0 + 8 * b < end) {
                float p = q4.x * __uint_as_float(kv[b].x & 0xFFFF0000u)
                        + q4.y * __uint_as_float(kv[b].y & 0xFFFF0000u)
                        + q4.z * __uint_as_float(kv[b].z & 0xFFFF0000u)
                        + q4.w * __uint_as_float(kv[b].w & 0xFFFF0000u);
#pragma unroll
                for (int ofs = 1; ofs < 8; ofs <<= 1)
                    p += __shfl_xor(p, ofs, 64);
                const float ex = (e0 + 8 * b + slot < end) ? __expf(p * scale) : 0.f;
                accD += ex;
                n0 += ex * __uint_as_float(kv[b].x << 16);
                n1 += ex * __uint_as_float(kv[b].y << 16);
                n2 += ex * __uint_as_float(kv[b].z << 16);
                n3 += ex * __uint_as_float(kv[b].w << 16);
            }
        }
    }

    // reduce over the 8 slots
#pragma unroll
    for (int ofs = 8; ofs < 64; ofs <<= 1) {
        accD += __shfl_xor(accD, ofs, 64);
        n0 += __shfl_xor(n0, ofs, 64);
        n1 += __shfl_xor(n1, ofs, 64);
        n2 += __shfl_xor(n2, ofs, 64);
        n3 += __shfl_xor(n3, ofs, 64);
    }

    if (slot == 0) {
        const float inv = (accD > 0.f) ? 1.f / accD : 0.f;
        float4 o;
        o.x = n0 * inv; o.y = n1 * inv; o.z = n2 * inv; o.w = n3 * inv;
        *(float4*)(out + r * HS + comp * 4) = o;
    }
}

extern "C" void kernel_launch(void* const* d_in, const int* in_sizes, int n_in,
                              void* d_out, int out_size, void* d_ws, size_t ws_size,
                              hipStream_t stream)
{
    const float* X  = (const float*)d_in[0];
    const float* Wq = (const float*)d_in[1];
    const float* Wk = (const float*)d_in[2];
    const float* Wv = (const float*)d_in[3];
    const int*   ei = (const int*)d_in[4];
    const int* er = ei;
    const int* ec = ei + N_EDGES;

    float* out = (float*)d_out;

    // workspace: Q | KVp | fill | rowptr | wfrag | pairs | col_sorted
    float* Q          = (float*)d_ws;
    unsigned int* KVp = (unsigned int*)(Q + (size_t)N_NODES * HS);
    int* fill         = (int*)(KVp + (size_t)N_NODES * HS);
    int* rowptr       = fill + NB;
    unsigned short* wfrag = (unsigned short*)(rowptr + (N_NODES + 1));
    unsigned int* pairs   = (unsigned int*)(wfrag + 8 * 6 * 64 * 8);
    int* col_sorted   = (int*)(pairs + (size_t)NB * CAP);

    wfrag_kernel<<<(8 * 6 * 64 * 8 + 255) / 256, 256, 0, stream>>>(
        Wq, Wk, Wv, wfrag, fill, rowptr);

    proj_bin_kernel<<<PROJ_B + BIN_B, 256, 0, stream>>>(
        X, wfrag, Q, KVp, er, ec, fill, pairs);

    place_kernel<<<NB, 256, 0, stream>>>(pairs, fill, rowptr, col_sorted);

    aggregate_kernel<<<(N_NODES * 64 + 255) / 256, 256, 0, stream>>>(
        rowptr, col_sorted, Q, KVp, out);
}